// Round 11
// baseline (564.184 us; speedup 1.0000x reference)
//
#include <hip/hip_runtime.h>
#include <stdint.h>

typedef unsigned short u16;
typedef __bf16 bf16x8 __attribute__((ext_vector_type(8)));
typedef float f32x4 __attribute__((ext_vector_type(4)));

#define LOG2E 1.4426950408889634f

__device__ __forceinline__ float bf2f(u16 a) {
  union { unsigned u; float f; } v; v.u = ((unsigned)a) << 16; return v.f;
}
__device__ __forceinline__ u16 f2bf(float f) {
  union { float f; unsigned u; } v; v.f = f;
  unsigned r = v.u + 0x7fffu + ((v.u >> 16) & 1u);
  return (u16)(r >> 16);
}
// native RTNE f32->bf16 (single v_cvt op vs ~4-op bit-twiddle)
__device__ __forceinline__ u16 f2bf_fast(float f) {
  __bf16 h = (__bf16)f;
  union { __bf16 h; u16 u; } v; v.h = h; return v.u;
}
// async global->LDS, 16B/lane. LDS dest = wave-uniform base + lane*16.
// NOTE: global source address is PER-LANE -> row-gather staging is free.
__device__ __forceinline__ void gl_lds16(const void* g, void* l) {
  __builtin_amdgcn_global_load_lds(
      (const __attribute__((address_space(1))) uint32_t*)g,
      (__attribute__((address_space(3))) uint32_t*)l,
      16, 0, 0);
}

__device__ __forceinline__ int swzf(int row) { return (row ^ (row >> 2)) & 7; }
// 64-col (128B-row) tiles: XOR f(row) into the 3-bit 16B-chunk index.
__device__ __forceinline__ int swz(int row, int colu16) {
  return row * 64 + (colu16 ^ (swzf(row) << 3));
}
// 128-col (256B-row) tiles: chunk index is 4 bits; XOR f(row) into low 3.
// Rows r and r+8 share a slot -> 2 lanes/bank-pair = free (m136).
__device__ __forceinline__ int swz128(int row, int colu16) {
  return row * 128 + (colu16 ^ (swzf(row) << 3));
}

// ---------------------------------------------------------------------------
// GEMM: acc = A[M,K] @ Bt[N,K]^T  (bf16 in, fp32 accum), async LDS staging.
// BK=64, 4 waves 2x2, mfma 16x16x32 bf16, XCD-aware block swizzle,
// XOR-swizzled LDS (round 9: conflicts 9.4e6 -> 0). 64x128 tile everywhere
// (round 10: 128^2 neutral — rowcnt early-exit leaves ~1.1 live blocks/CU).
// rowcnt: per-batch valid M rows; rounds to ceil128 (attn KVBLK=128 reads
// K rows up to ceil128(nv) — they must be computed & finite).
// MODE: 0 bf16 C=acc | 1 bf16 C=acc+bias+res (o-proj, C may alias res)
//       2 bf16 C=relu(acc+bias) | 3 f32 C32=acc+bias+resx+bf2f(resbf)
//       4 f32 C32+=acc
// ---------------------------------------------------------------------------
template <int BM, int BN, int MODE>
__global__ __launch_bounds__(256) void gemm_bt(
    const u16* __restrict__ A, const u16* __restrict__ Bt,
    u16* Cbf, float* C32,
    const float* __restrict__ bias,
    const u16* resbf, const float* __restrict__ resx,
    int M, int N, int K, const int* __restrict__ rowcnt)
{
  constexpr int MT = BM / 32, NT = BN / 32;
  constexpr int GA = BM / 32, GB = BN / 32;   // 16B chunks: BM*8/256 per iter
  __shared__ u16 sA[BM * 64];
  __shared__ u16 sB[BN * 64];
  const int tid  = threadIdx.x;
  const int wave = tid >> 6, lane = tid & 63;
  const int quad = lane >> 4, l16 = lane & 15;
  const int wm = wave >> 1, wn = wave & 1;
  // XCD swizzle: linear id -> contiguous chunk per XCD
  const int nwg = gridDim.x * gridDim.y;
  const int bid = blockIdx.y * gridDim.x + blockIdx.x;
  const int sw  = (bid & 7) * (nwg >> 3) + (bid >> 3);
  const int m0 = (sw / gridDim.x) * BM, n0 = (sw % gridDim.x) * BN;
  if (rowcnt) {  // compacted-M early exit (batch band = 1024 rows)
    int lim = (rowcnt[m0 >> 10] + 127) & ~127;  // ceil128: attn coverage
    if ((m0 & 1023) >= lim) return;
  }

  f32x4 acc[MT][NT] = {};

  for (int k0 = 0; k0 < K; k0 += 64) {
    __syncthreads();  // prev tile's LDS reads done
#pragma unroll
    for (int i = 0; i < GA; ++i) {
      int cb = i * 256 + wave * 64;   // wave-uniform LDS chunk base
      int c = cb + lane;
      int row = c >> 3;
      int kcs = (c & 7) ^ swzf(row);  // pre-swizzled source
      gl_lds16(A + (size_t)(m0 + row) * K + k0 + kcs * 8, &sA[cb * 8]);
    }
#pragma unroll
    for (int i = 0; i < GB; ++i) {
      int cb = i * 256 + wave * 64;
      int c = cb + lane;
      int row = c >> 3;
      int kcs = (c & 7) ^ swzf(row);
      gl_lds16(Bt + (size_t)(n0 + row) * K + k0 + kcs * 8, &sB[cb * 8]);
    }
    __syncthreads();  // barrier waitcnt drains vmcnt(0): staging complete

#pragma unroll
    for (int kk = 0; kk < 2; ++kk) {
      bf16x8 fa[MT], fb[NT];
#pragma unroll
      for (int mt = 0; mt < MT; ++mt)
        fa[mt] = *(const bf16x8*)&sA[swz(wm * (BM / 2) + mt * 16 + l16, kk * 32 + quad * 8)];
#pragma unroll
      for (int nt = 0; nt < NT; ++nt)
        fb[nt] = *(const bf16x8*)&sB[swz(wn * (BN / 2) + nt * 16 + l16, kk * 32 + quad * 8)];
#pragma unroll
      for (int mt = 0; mt < MT; ++mt)
#pragma unroll
        for (int nt = 0; nt < NT; ++nt)
          acc[mt][nt] = __builtin_amdgcn_mfma_f32_16x16x32_bf16(
              fa[mt], fb[nt], acc[mt][nt], 0, 0, 0);
    }
  }

  // epilogue: C layout col=lane&15, row=quad*4+reg
#pragma unroll
  for (int mt = 0; mt < MT; ++mt) {
#pragma unroll
    for (int nt = 0; nt < NT; ++nt) {
#pragma unroll
      for (int r = 0; r < 4; ++r) {
        int row = m0 + wm * (BM / 2) + mt * 16 + quad * 4 + r;
        int col = n0 + wn * (BN / 2) + nt * 16 + l16;
        size_t idx = (size_t)row * N + col;
        float v = acc[mt][nt][r];
        if constexpr (MODE == 0) {
          Cbf[idx] = f2bf(v);
        } else if constexpr (MODE == 1) {
          v += bias[col] + bf2f(resbf[idx]);
          Cbf[idx] = f2bf(v);
        } else if constexpr (MODE == 2) {
          v = fmaxf(v + bias[col], 0.f);
          Cbf[idx] = f2bf(v);
        } else if constexpr (MODE == 3) {
          v += bias[col] + resx[idx] + bf2f(resbf[idx]);
          C32[idx] = v;
        } else {
          C32[idx] = C32[idx] + v;
        }
      }
    }
  }
}

// ---------------------------------------------------------------------------
// 64x64-tiled transpose + fp32->bf16 cast: out[c][r] = (bf16)in[r][c].
// ---------------------------------------------------------------------------
__global__ __launch_bounds__(256) void transpose64(
    const float* __restrict__ in, u16* __restrict__ out, int R, int Cstride)
{
  __shared__ u16 tile[64][72];
  const int r0 = blockIdx.y * 64, c0 = blockIdx.x * 64;
  const int t = threadIdx.x;
  {
    const int lr = t >> 4, lc = (t & 15) * 4;
#pragma unroll
    for (int h = 0; h < 4; ++h) {
      int row = h * 16 + lr;
      float4 vd = *(const float4*)&in[(size_t)(r0 + row) * Cstride + c0 + lc];
      ushort4 ov;
      ov.x = f2bf(vd.x); ov.y = f2bf(vd.y); ov.z = f2bf(vd.z); ov.w = f2bf(vd.w);
      *(ushort4*)&tile[row][lc] = ov;
    }
  }
  __syncthreads();
  {
    const int lr = t >> 3, lv = t & 7;
#pragma unroll
    for (int h = 0; h < 2; ++h) {
      int orow = h * 32 + lr;
      u16 tmp[8];
#pragma unroll
      for (int j = 0; j < 8; ++j) tmp[j] = tile[lv * 8 + j][orow];
      *(uint4*)&out[(size_t)(c0 + orow) * R + r0 + lv * 8] = *(uint4*)tmp;
    }
  }
}

// ---------------------------------------------------------------------------
// Mask scan: per batch b, sidx[b][0..nv) = indices of valid (mask!=0) s2
// positions in ascending order; nv[b] = count. One block per b.
// ---------------------------------------------------------------------------
__global__ __launch_bounds__(256) void mask_scan(
    const int* __restrict__ mask, int* __restrict__ sidx, int* __restrict__ nv)
{
  const int b = blockIdx.x, t = threadIdx.x;
  const int wave = t >> 6, lane = t & 63;
  int m[4]; int cnt = 0;
#pragma unroll
  for (int k = 0; k < 4; ++k) { m[k] = (mask[b * 1024 + t * 4 + k] != 0); cnt += m[k]; }
  int sc = cnt;  // inclusive wave scan
  for (int sh = 1; sh < 64; sh <<= 1) {
    int u = __shfl_up(sc, sh);
    if (lane >= sh) sc += u;
  }
  __shared__ int wsum[4];
  if (lane == 63) wsum[wave] = sc;
  __syncthreads();
  int woff = 0;
  for (int w = 0; w < wave; ++w) woff += wsum[w];
  int pos = woff + sc - cnt;  // exclusive prefix
#pragma unroll
  for (int k = 0; k < 4; ++k)
    if (m[k]) sidx[b * 1024 + pos++] = t * 4 + k;
  if (t == 255) nv[b] = wsum[0] + wsum[1] + wsum[2] + wsum[3];
}

// ---------------------------------------------------------------------------
// Row gather: dst[b*1024+i] = src[b*1024 + sidx[min(i, nv-1)]] (bf16 rows of
// 1024). Pads tail rows with duplicates of the last valid row (finite data).
// Grid 1024, one row per wave.
// ---------------------------------------------------------------------------
__global__ __launch_bounds__(256) void gather_kv(
    const u16* __restrict__ src, const int* __restrict__ sidx,
    const int* __restrict__ nv, u16* __restrict__ dst)
{
  const int t = threadIdx.x, wave = t >> 6, lane = t & 63;
  const int row = blockIdx.x * 4 + wave;
  const int b = row >> 10, i = row & 1023;
  const int n = nv[b];
  const int s = sidx[b * 1024 + (i < n ? i : n - 1)];
  const uint4* sp = (const uint4*)&src[((size_t)(b << 10) + s) * 1024];
  uint4* dp = (uint4*)&dst[(size_t)row * 1024];
  dp[lane] = sp[lane];
  dp[lane + 64] = sp[lane + 64];
}

// ---------------------------------------------------------------------------
// Compacted V^T from compacted kvbuf v-half: out[(b*16+h)*64+d][i] =
// kvbuf[b*1024+min(i,n-1)][1024+h*64+d]. Clamp keeps all columns finite.
// ---------------------------------------------------------------------------
__global__ __launch_bounds__(256) void vtc_kernel(
    const u16* __restrict__ in, const int* __restrict__ nv,
    u16* __restrict__ out)
{
  __shared__ u16 tile[64][72];
  const int st = blockIdx.x, bh = blockIdx.y;
  const int b = bh >> 4, h = bh & 15;
  const int t = threadIdx.x;
  const int lr = t >> 3, lv = t & 7;
  const int n = nv[b];
  const u16* srcb = in + (size_t)b * 1024 * 2048 + 1024 + h * 64;
#pragma unroll
  for (int half = 0; half < 2; ++half) {
    int i = st * 64 + half * 32 + lr;               // compacted s2 index
    int s = i < n ? i : n - 1;                      // clamp -> finite data
    uint4 vd = *(const uint4*)&srcb[(size_t)s * 2048 + lv * 8];
    *(uint4*)&tile[half * 32 + lr][lv * 8] = vd;
  }
  __syncthreads();
  u16* dst = out + (size_t)bh * 64 * 1024 + st * 64;
#pragma unroll
  for (int half = 0; half < 2; ++half) {
    int orow = half * 32 + lr;  // d
    u16 tmp[8];
#pragma unroll
    for (int j = 0; j < 8; ++j) tmp[j] = tile[lv * 8 + j][orow];
    *(uint4*)&dst[(size_t)orow * 1024 + lv * 8] = *(uint4*)tmp;
  }
}

// ---------------------------------------------------------------------------
// LayerNorm over D=1024, fp32 in -> bf16 out.
// ---------------------------------------------------------------------------
__global__ __launch_bounds__(256) void ln_kernel(
    const float* __restrict__ x, const float* __restrict__ g,
    const float* __restrict__ b, u16* __restrict__ outbf)
{
  const int row = blockIdx.x, t = threadIdx.x;
  const int wave = t >> 6, lane = t & 63;
  float4 xv = *(const float4*)&x[(size_t)row * 1024 + t * 4];
  float v0 = xv.x, v1 = xv.y, v2 = xv.z, v3 = xv.w;
  float s = v0 + v1 + v2 + v3;
  float s2 = v0 * v0 + v1 * v1 + v2 * v2 + v3 * v3;
  for (int m = 1; m < 64; m <<= 1) { s += __shfl_xor(s, m); s2 += __shfl_xor(s2, m); }
  __shared__ float ps[4], pq[4];
  if (lane == 0) { ps[wave] = s; pq[wave] = s2; }
  __syncthreads();
  s = ps[0] + ps[1] + ps[2] + ps[3];
  s2 = pq[0] + pq[1] + pq[2] + pq[3];
  float mean = s * (1.f / 1024.f);
  float var = s2 * (1.f / 1024.f) - mean * mean;
  float rs = rsqrtf(var + 1e-5f);
  float4 gv = *(const float4*)&g[t * 4];
  float4 bv = *(const float4*)&b[t * 4];
  ushort4 ov;
  ov.x = f2bf((v0 - mean) * rs * gv.x + bv.x);
  ov.y = f2bf((v1 - mean) * rs * gv.y + bv.y);
  ov.z = f2bf((v2 - mean) * rs * gv.z + bv.z);
  ov.w = f2bf((v3 - mean) * rs * gv.w + bv.w);
  *(ushort4*)&outbf[(size_t)row * 1024 + t * 4] = ov;
}

// h = LN(x + y), x fp32, y bf16.
__global__ __launch_bounds__(256) void ln_add_kernel(
    const float* __restrict__ x, const u16* __restrict__ ybf,
    const float* __restrict__ g, const float* __restrict__ b,
    u16* __restrict__ hbf)
{
  const int row = blockIdx.x, t = threadIdx.x;
  const int wave = t >> 6, lane = t & 63;
  float4 xv = *(const float4*)&x[(size_t)row * 1024 + t * 4];
  ushort4 yv = *(const ushort4*)&ybf[(size_t)row * 1024 + t * 4];
  float v0 = xv.x + bf2f(yv.x), v1 = xv.y + bf2f(yv.y);
  float v2 = xv.z + bf2f(yv.z), v3 = xv.w + bf2f(yv.w);
  float s = v0 + v1 + v2 + v3;
  float s2 = v0 * v0 + v1 * v1 + v2 * v2 + v3 * v3;
  for (int m = 1; m < 64; m <<= 1) { s += __shfl_xor(s, m); s2 += __shfl_xor(s2, m); }
  __shared__ float ps[4], pq[4];
  if (lane == 0) { ps[wave] = s; pq[wave] = s2; }
  __syncthreads();
  s = ps[0] + ps[1] + ps[2] + ps[3];
  s2 = pq[0] + pq[1] + pq[2] + pq[3];
  float mean = s * (1.f / 1024.f);
  float var = s2 * (1.f / 1024.f) - mean * mean;
  float rs = rsqrtf(var + 1e-5f);
  float4 gv = *(const float4*)&g[t * 4];
  float4 bv = *(const float4*)&b[t * 4];
  ushort4 ov;
  ov.x = f2bf((v0 - mean) * rs * gv.x + bv.x);
  ov.y = f2bf((v1 - mean) * rs * gv.y + bv.y);
  ov.z = f2bf((v2 - mean) * rs * gv.z + bv.z);
  ov.w = f2bf((v3 - mean) * rs * gv.w + bv.w);
  *(ushort4*)&hbf[(size_t)row * 1024 + t * 4] = ov;
}

// ---------------------------------------------------------------------------
// Flash-style cross-attention v9: KVBLK=128 (was 64). Per iter 32KB staged
// feeds 2x MFMA (same FLOP/byte) but jmax halves to ceil(nv/128) ~4-5 ->
// half the serialized barrier+vmcnt drains (round-10 counters: 60% of attn
// cycles issue nothing at 2 blocks/CU). LDS 64KB: sK[128][64] (swz),
// sVt[64][128] + sP[128][128] (swz128, 256B rows). QBLK=128, 4 waves,
// XCD-local grid, direct compacted K/V rows.
// ---------------------------------------------------------------------------
__global__ __launch_bounds__(256) void attn_kernel(
    const u16* __restrict__ Q,   // [b*1024+s1][1024], head offset h*64
    const u16* __restrict__ K,   // compacted kvbuf [b*1024+i][2048], h*64
    const u16* __restrict__ Vt,  // compacted [(b*16+h)*64+d][1024]
    const int* __restrict__ nvp,
    u16* __restrict__ O)         // [b*1024+s1][1024]
{
  __shared__ u16 sK[128 * 64], sVt[64 * 128], sP[128 * 128];
  const int h = blockIdx.x, qt = blockIdx.y, b = blockIdx.z;
  const int t = threadIdx.x;
  const int wave = t >> 6, lane = t & 63;
  const int quad = lane >> 4, l16 = lane & 15;
  const u16* Qb = Q + (size_t)b * 1024 * 1024 + (size_t)qt * 128 * 1024 + h * 64;
  const u16* Kb = K + (size_t)b * 1024 * 2048 + h * 64;
  const u16* Vb = Vt + (size_t)(b * 16 + h) * 64 * 1024;
  const int n = nvp[b];
  const int jmax = (n + 127) >> 7;

  // stage Q [128 s1][64 dk] into sP's first 16KB (64-col swz convention)
#pragma unroll
  for (int i = 0; i < 4; ++i) {
    int cb = i * 256 + wave * 64;
    int c = cb + lane;
    int row = c >> 3;
    int scc = (c & 7) ^ swzf(row);
    gl_lds16(Qb + (size_t)row * 1024 + scc * 8, &sP[cb * 8]);
  }
  __syncthreads();  // drain Q staging (cross-wave)
  bf16x8 aq[2][2];
#pragma unroll
  for (int g = 0; g < 2; ++g)
#pragma unroll
    for (int ks = 0; ks < 2; ++ks)
      aq[g][ks] = *(const bf16x8*)&sP[swz(wave * 32 + g * 16 + l16, ks * 32 + quad * 8)];

  float m2_[2][4], l_[2][4];
  f32x4 accO[2][4] = {};
#pragma unroll
  for (int g = 0; g < 2; ++g)
#pragma unroll
    for (int r = 0; r < 4; ++r) { m2_[g][r] = -1e30f; l_[g][r] = 0.f; }

  constexpr float QS = 0.125f * LOG2E;  // scale folded into base-2 domain

  for (int j = 0; j < jmax; ++j) {
    __syncthreads();  // prev iter's sK/sVt reads (and aq reads at j=0) done
    // sK [128 s2][64 dk]: rows j*128.. < ceil128(n), all computed (gemm lim).
#pragma unroll
    for (int i = 0; i < 4; ++i) {
      int cb = i * 256 + wave * 64;
      int c = cb + lane;
      int row = c >> 3;                 // 0..127
      int scc = (c & 7) ^ swzf(row);
      gl_lds16(Kb + (size_t)(j * 128 + row) * 2048 + scc * 8, &sK[cb * 8]);
    }
    // sVt [64 d][128 s2]: 16 chunks/row, 4-bit chunk idx, XOR low 3 bits.
#pragma unroll
    for (int i = 0; i < 4; ++i) {
      int cb = i * 256 + wave * 64;
      int c = cb + lane;
      int row = c >> 4;                 // 0..63 (d)
      int scc = (c & 15) ^ swzf(row);
      gl_lds16(Vb + (size_t)row * 1024 + j * 128 + scc * 8, &sVt[cb * 8]);
    }
    __syncthreads();  // drains vmcnt: sK/sVt staged

    float mf[8];
#pragma unroll
    for (int nt = 0; nt < 8; ++nt)
      mf[nt] = (j * 128 + nt * 16 + l16 < n) ? 0.f : -1e9f;

    // per 16-row group: S = Q K^T (128 s2 cols), online softmax, P -> sP
#pragma unroll
    for (int g = 0; g < 2; ++g) {
      f32x4 accS[8] = {};
#pragma unroll
      for (int ks = 0; ks < 2; ++ks) {
#pragma unroll
        for (int nt = 0; nt < 8; ++nt) {
          bf16x8 bk = *(const bf16x8*)&sK[swz(nt * 16 + l16, ks * 32 + quad * 8)];
          accS[nt] = __builtin_amdgcn_mfma_f32_16x16x32_bf16(aq[g][ks], bk, accS[nt], 0, 0, 0);
        }
      }
      float vv[4][8], cm_[4];
      bool need = false;
#pragma unroll
      for (int r = 0; r < 4; ++r) {
        float cm = -1e30f;
#pragma unroll
        for (int nt = 0; nt < 8; ++nt) {
          vv[r][nt] = fmaf(accS[nt][r], QS, mf[nt]);
          cm = fmaxf(cm, vv[r][nt]);
        }
        for (int sh = 1; sh < 16; sh <<= 1) cm = fmaxf(cm, __shfl_xor(cm, sh));
        cm_[r] = cm;
        need = need || (cm > m2_[g][r] + 8.f);
      }
      if (__any(need)) {  // T13 defer-max: rescale only when a max grew by >8
#pragma unroll
        for (int r = 0; r < 4; ++r) {
          float nm = fmaxf(m2_[g][r], cm_[r]);
          float al = exp2f(m2_[g][r] - nm);
          m2_[g][r] = nm;
          l_[g][r] *= al;
#pragma unroll
          for (int n2 = 0; n2 < 4; ++n2) accO[g][n2][r] *= al;
        }
      }
#pragma unroll
      for (int r = 0; r < 4; ++r) {
        int prow = wave * 32 + g * 16 + quad * 4 + r;
        float rs = 0.f;
#pragma unroll
        for (int nt = 0; nt < 8; ++nt) {
          float p = exp2f(vv[r][nt] - m2_[g][r]);
          rs += p;
          sP[swz128(prow, nt * 16 + l16)] = f2bf_fast(p);
        }
        l_[g][r] += rs;  // per-lane partial sum; reduced after the loop
      }
    }
    // O += P @ V over 128 s2 (ks 0..3). No barrier: sP rows wave-private;
    // V frags shared across both row groups.
#pragma unroll
    for (int ks = 0; ks < 4; ++ks) {
      bf16x8 bv[4];
#pragma unroll
      for (int n2 = 0; n2 < 4; ++n2)
        bv[n2] = *(const bf16x8*)&sVt[swz128(n2 * 16 + l16, ks * 32 + quad * 8)];
#pragma unroll
      for (int g = 0; g < 2; ++g) {
        bf16x8 ap = *(const bf16x8*)&sP[swz128(wave * 32 + g * 16 + l16, ks * 32 + quad * 8)];
#pragma unroll
        for (int n2 = 0; n2 < 4; ++n2)
          accO[g][n2] = __builtin_amdgcn_mfma_f32_16x16x32_bf16(ap, bv[n2], accO[g][n2], 0, 0, 0);
      }
    }
  }

  // final l reduce across the 16 l16 lanes of each row (deferred from loop)
  u16* Ob = O + (size_t)b * 1024 * 1024 + (size_t)qt * 128 * 1024 + h * 64;
#pragma unroll
  for (int g = 0; g < 2; ++g) {
#pragma unroll
    for (int r = 0; r < 4; ++r) {
      float lr = l_[g][r];
      for (int sh = 1; sh < 16; sh <<= 1) lr += __shfl_xor(lr, sh);
      float inv = 1.f / lr;
      int row = wave * 32 + g * 16 + quad * 4 + r;
#pragma unroll
      for (int n2 = 0; n2 < 4; ++n2)
        Ob[(size_t)row * 1024 + n2 * 16 + l16] = f2bf_fast(accO[g][n2][r] * inv);
    }
  }
}

// ---------------------------------------------------------------------------
extern "C" void kernel_launch(void* const* d_in, const int* in_sizes, int n_in,
                              void* d_out, int out_size, void* d_ws, size_t ws_size,
                              hipStream_t stream)
{
  const float* x   = (const float*)d_in[0];
  const float* kv  = (const float*)d_in[1];
  const int* attn_bias = (const int*)d_in[2];
  const float* ln1_g = (const float*)d_in[3];
  const float* ln1_b = (const float*)d_in[4];
  const float* qw0 = (const float*)d_in[5];
  const float* kw0 = (const float*)d_in[6];
  const float* vw0 = (const float*)d_in[7];
  const float* ow0 = (const float*)d_in[8];
  const float* ob0 = (const float*)d_in[9];
  const float* qw1 = (const float*)d_in[10];
  const float* kw1 = (const float*)d_in[11];
  const float* vw1 = (const float*)d_in[12];
  const float* ow1 = (const float*)d_in[13];
  const float* ob1 = (const float*)d_in[14];
  const float* ln2_g = (const float*)d_in[15];
  const float* ln2_b = (const float*)d_in[16];
  const float* w1 = (const float*)d_in[17];
  const float* b1 = (const float*)d_in[18];
  const float* w2 = (const float*)d_in[19];
  const float* b2 = (const float*)d_in[20];

  // ---- workspace: 48 MB peak (proven safe), d_out doubles as scratch ----
  char* ws = (char*)d_ws;
  const size_t MB = 1u << 20;
  u16* Wkv   = (u16*)(ws + 0 * MB);    // stacked kv weight-T [2048,1024] 4MB
  u16* Wsm   = (u16*)(ws + 4 * MB);    // q/o weight-T [1024,1024] 2MB (serial)
  int* sidx  = (int*)(ws + 6 * MB);    // 16KB+16B (free gap; FFN reuses later)
  int* nvp   = sidx + 4096;
  u16* wtA   = (u16*)(ws + 0 * MB);    // FFN band w1-T [2048,1024] 4MB
  u16* wtB   = (u16*)(ws + 4 * MB);    // FFN band w2-T [1024,2048] 4MB
  u16* ybf   = (u16*)(ws + 8 * MB);    // residual y bf16 8MB
  u16* kvc   = (u16*)(ws + 16 * MB);   // compacted LN1(kv) 8MB; hbf aliases
  u16* qbuf  = (u16*)(ws + 24 * MB);   // q bf16 8MB (also LN1(kv) temp)
  u16* kvbuf = (u16*)(ws + 32 * MB);   // [4096,2048] k|v compacted 16MB
  u16* hbf   = kvc;                    // ln_add output (kvc dead by then)
  u16* fbuf  = kvbuf;                  // [4096,2048] bf16 16MB
  u16* attnb = (u16*)d_out;                      // lower 8MB of d_out
  u16* vT    = (u16*)((char*)d_out + 8 * MB);    // upper 8MB of d_out
  float* out32 = (float*)d_out;

  const dim3 B256(256);
  const dim3 gT(16, 16);         // 1024x1024 weight transpose
  const dim3 gGemmN1k(8, 64);    // <64,128>  N=1024: 512 blocks
  const dim3 gGemm2k(16, 64);    // <64,128>  N=2048: 1024 blocks (round 9)
  const dim3 gVt(16, 64);
  const dim3 gAttn(16, 8, 4);    // (h, qt, b): qt stride 16 = 0 mod 8 XCDs

  // --- mask compaction (mask is layer-invariant: run once) ---
  mask_scan<<<4, B256, 0, stream>>>(attn_bias, sidx, nvp);

  // --- LN1; kv normed into qbuf (temp), then row-compacted into kvc ---
  ln_kernel<<<4096, B256, 0, stream>>>(x,  ln1_g, ln1_b, ybf);
  ln_kernel<<<4096, B256, 0, stream>>>(kv, ln1_g, ln1_b, qbuf);
  gather_kv<<<1024, B256, 0, stream>>>(qbuf, sidx, nvp, kvc);

  for (int layer = 0; layer < 2; ++layer) {
    const float* qw = layer ? qw1 : qw0;
    const float* kw = layer ? kw1 : kw0;
    const float* vw = layer ? vw1 : vw0;
    const float* ow = layer ? ow1 : ow0;
    const float* ob = layer ? ob1 : ob0;

    // fused k|v projection on COMPACTED rows: Wkv = [kw^T ; vw^T]
    transpose64<<<gT, B256, 0, stream>>>(kw, Wkv, 1024, 1024);
    transpose64<<<gT, B256, 0, stream>>>(vw, Wkv + 1024 * 1024, 1024, 1024);
    gemm_bt<64, 128, 0><<<gGemm2k, B256, 0, stream>>>(
        kvc, Wkv, kvbuf, nullptr, nullptr, nullptr, nullptr,
        4096, 2048, 1024, nvp);
    // q projection
    transpose64<<<gT, B256, 0, stream>>>(qw, Wsm, 1024, 1024);
    gemm_bt<64, 128, 0><<<gGemmN1k, B256, 0, stream>>>(
        ybf, Wsm, qbuf, nullptr, nullptr, nullptr, nullptr,
        4096, 1024, 1024, nullptr);
    // compacted V^T materialization from compacted kvbuf v-half
    vtc_kernel<<<gVt, B256, 0, stream>>>(kvbuf, nvp, vT);

    attn_kernel<<<gAttn, B256, 0, stream>>>(qbuf, kvbuf, vT, nvp, attnb);

    // y = attn_out @ ow + ob + y
    transpose64<<<gT, B256, 0, stream>>>(ow, Wsm, 1024, 1024);
    gemm_bt<64, 128, 1><<<gGemmN1k, B256, 0, stream>>>(
        attnb, Wsm, ybf, nullptr, ob, ybf, nullptr,
        4096, 1024, 1024, nullptr);
  }

  // --- h = LN2(x + y) ---
  ln_add_kernel<<<4096, B256, 0, stream>>>(x, ybf, ln2_g, ln2_b, hbf);

  // --- FFN in two K-bands of 2048; fp32 accumulate into d_out ---
  for (int band = 0; band < 2; ++band) {
    transpose64<<<dim3(32, 16), B256, 0, stream>>>(w1 + band * 2048, wtA, 1024, 4096);
    transpose64<<<dim3(16, 32), B256, 0, stream>>>(w2 + (size_t)band * 2048 * 1024,
                                                   wtB, 2048, 1024);
    gemm_bt<64, 128, 2><<<gGemm2k, B256, 0, stream>>>(
        hbf, wtA, fbuf, nullptr, b1 + band * 2048, nullptr, nullptr,
        4096, 2048, 1024, nullptr);
    if (band == 0) {
      gemm_bt<64, 128, 3><<<gGemmN1k, B256, 0, stream>>>(
          fbuf, wtB, nullptr, out32, b2, ybf, x, 4096, 1024, 2048, nullptr);
    } else {
      gemm_bt<64, 128, 4><<<gGemmN1k, B256, 0, stream>>>(
          fbuf, wtB, nullptr, out32, nullptr, nullptr, nullptr,
          4096, 1024, 2048, nullptr);
    }
  }
}

// Round 13
// 519.290 us; speedup vs baseline: 1.0865x; 1.0865x over previous
//
#include <hip/hip_runtime.h>
#include <stdint.h>

typedef unsigned short u16;
typedef __bf16 bf16x8 __attribute__((ext_vector_type(8)));
typedef float f32x4 __attribute__((ext_vector_type(4)));

#define LOG2E 1.4426950408889634f

__device__ __forceinline__ float bf2f(u16 a) {
  union { unsigned u; float f; } v; v.u = ((unsigned)a) << 16; return v.f;
}
__device__ __forceinline__ u16 f2bf(float f) {
  union { float f; unsigned u; } v; v.f = f;
  unsigned r = v.u + 0x7fffu + ((v.u >> 16) & 1u);
  return (u16)(r >> 16);
}
// native RTNE f32->bf16 (single v_cvt op vs ~4-op bit-twiddle)
__device__ __forceinline__ u16 f2bf_fast(float f) {
  __bf16 h = (__bf16)f;
  union { __bf16 h; u16 u; } v; v.h = h; return v.u;
}
// async global->LDS, 16B/lane. LDS dest = wave-uniform base + lane*16.
// NOTE: global source address is PER-LANE -> row-gather staging is free.
__device__ __forceinline__ void gl_lds16(const void* g, void* l) {
  __builtin_amdgcn_global_load_lds(
      (const __attribute__((address_space(1))) uint32_t*)g,
      (__attribute__((address_space(3))) uint32_t*)l,
      16, 0, 0);
}

__device__ __forceinline__ int swzf(int row) { return (row ^ (row >> 2)) & 7; }
// XOR swizzle for [R][64] bf16 tiles (128B rows): f(row) into the 3-bit
// 16B-chunk index; applied to BOTH staged global source chunk and every LDS
// read/write (involution). 16 consecutive rows -> 8 slots -> 2-way = free.
__device__ __forceinline__ int swz(int row, int colu16) {
  return row * 64 + (colu16 ^ (swzf(row) << 3));
}

// ---------------------------------------------------------------------------
// GEMM: acc = A[M,K] @ Bt[N,K]^T  (bf16 in, fp32 accum), async LDS staging.
// BK=64, 4 waves 2x2, mfma 16x16x32 bf16, XCD-aware block swizzle,
// XOR-swizzled LDS (round 9 proven: conflicts 9.4e6 -> 0, 534.2us total).
// 64x128 tile everywhere (round 10: 128^2 neutral; round 11: KVBLK=128
// regressed -> full revert to round-9 config).
// rowcnt: per-batch valid M rows, ceil64 (attn KVBLK=64 coverage).
// MODE: 0 bf16 C=acc | 1 bf16 C=acc+bias+res (o-proj, C may alias res)
//       2 bf16 C=relu(acc+bias) | 3 f32 C32=acc+bias+resx+bf2f(resbf)
//       4 f32 C32+=acc
// ---------------------------------------------------------------------------
template <int BM, int BN, int MODE>
__global__ __launch_bounds__(256) void gemm_bt(
    const u16* __restrict__ A, const u16* __restrict__ Bt,
    u16* Cbf, float* C32,
    const float* __restrict__ bias,
    const u16* resbf, const float* __restrict__ resx,
    int M, int N, int K, const int* __restrict__ rowcnt)
{
  constexpr int MT = BM / 32, NT = BN / 32;
  constexpr int GA = BM / 32, GB = BN / 32;   // 16B chunks: BM*8/256 per iter
  __shared__ u16 sA[BM * 64];
  __shared__ u16 sB[BN * 64];
  const int tid  = threadIdx.x;
  const int wave = tid >> 6, lane = tid & 63;
  const int quad = lane >> 4, l16 = lane & 15;
  const int wm = wave >> 1, wn = wave & 1;
  // XCD swizzle: linear id -> contiguous chunk per XCD
  const int nwg = gridDim.x * gridDim.y;
  const int bid = blockIdx.y * gridDim.x + blockIdx.x;
  const int sw  = (bid & 7) * (nwg >> 3) + (bid >> 3);
  const int m0 = (sw / gridDim.x) * BM, n0 = (sw % gridDim.x) * BN;
  if (rowcnt) {  // compacted-M early exit (batch band = 1024 rows)
    int lim = (rowcnt[m0 >> 10] + 63) & ~63;
    if ((m0 & 1023) >= lim) return;
  }

  f32x4 acc[MT][NT] = {};

  for (int k0 = 0; k0 < K; k0 += 64) {
    __syncthreads();  // prev tile's LDS reads done
#pragma unroll
    for (int i = 0; i < GA; ++i) {
      int cb = i * 256 + wave * 64;   // wave-uniform LDS chunk base
      int c = cb + lane;
      int row = c >> 3;
      int kcs = (c & 7) ^ swzf(row);  // pre-swizzled source
      gl_lds16(A + (size_t)(m0 + row) * K + k0 + kcs * 8, &sA[cb * 8]);
    }
#pragma unroll
    for (int i = 0; i < GB; ++i) {
      int cb = i * 256 + wave * 64;
      int c = cb + lane;
      int row = c >> 3;
      int kcs = (c & 7) ^ swzf(row);
      gl_lds16(Bt + (size_t)(n0 + row) * K + k0 + kcs * 8, &sB[cb * 8]);
    }
    __syncthreads();  // barrier waitcnt drains vmcnt(0): staging complete

#pragma unroll
    for (int kk = 0; kk < 2; ++kk) {
      bf16x8 fa[MT], fb[NT];
#pragma unroll
      for (int mt = 0; mt < MT; ++mt)
        fa[mt] = *(const bf16x8*)&sA[swz(wm * (BM / 2) + mt * 16 + l16, kk * 32 + quad * 8)];
#pragma unroll
      for (int nt = 0; nt < NT; ++nt)
        fb[nt] = *(const bf16x8*)&sB[swz(wn * (BN / 2) + nt * 16 + l16, kk * 32 + quad * 8)];
#pragma unroll
      for (int mt = 0; mt < MT; ++mt)
#pragma unroll
        for (int nt = 0; nt < NT; ++nt)
          acc[mt][nt] = __builtin_amdgcn_mfma_f32_16x16x32_bf16(
              fa[mt], fb[nt], acc[mt][nt], 0, 0, 0);
    }
  }

  // epilogue: C layout col=lane&15, row=quad*4+reg
#pragma unroll
  for (int mt = 0; mt < MT; ++mt) {
#pragma unroll
    for (int nt = 0; nt < NT; ++nt) {
#pragma unroll
      for (int r = 0; r < 4; ++r) {
        int row = m0 + wm * (BM / 2) + mt * 16 + quad * 4 + r;
        int col = n0 + wn * (BN / 2) + nt * 16 + l16;
        size_t idx = (size_t)row * N + col;
        float v = acc[mt][nt][r];
        if constexpr (MODE == 0) {
          Cbf[idx] = f2bf(v);
        } else if constexpr (MODE == 1) {
          v += bias[col] + bf2f(resbf[idx]);
          Cbf[idx] = f2bf(v);
        } else if constexpr (MODE == 2) {
          v = fmaxf(v + bias[col], 0.f);
          Cbf[idx] = f2bf(v);
        } else if constexpr (MODE == 3) {
          v += bias[col] + resx[idx] + bf2f(resbf[idx]);
          C32[idx] = v;
        } else {
          C32[idx] = C32[idx] + v;
        }
      }
    }
  }
}

// ---------------------------------------------------------------------------
// 64x64-tiled transpose + fp32->bf16 cast: out[c][r] = (bf16)in[r][c].
// ---------------------------------------------------------------------------
__device__ __forceinline__ void transpose_body(
    const float* in, u16* out, int R, int Cstride, int bx, int by, int t)
{
  __shared__ u16 tile[64][72];
  const int r0 = by * 64, c0 = bx * 64;
  {
    const int lr = t >> 4, lc = (t & 15) * 4;
#pragma unroll
    for (int h = 0; h < 4; ++h) {
      int row = h * 16 + lr;
      float4 vd = *(const float4*)&in[(size_t)(r0 + row) * Cstride + c0 + lc];
      ushort4 ov;
      ov.x = f2bf(vd.x); ov.y = f2bf(vd.y); ov.z = f2bf(vd.z); ov.w = f2bf(vd.w);
      *(ushort4*)&tile[row][lc] = ov;
    }
  }
  __syncthreads();
  {
    const int lr = t >> 3, lv = t & 7;
#pragma unroll
    for (int h = 0; h < 2; ++h) {
      int orow = h * 32 + lr;
      u16 tmp[8];
#pragma unroll
      for (int j = 0; j < 8; ++j) tmp[j] = tile[lv * 8 + j][orow];
      *(uint4*)&out[(size_t)(c0 + orow) * R + r0 + lv * 8] = *(uint4*)tmp;
    }
  }
}

__global__ __launch_bounds__(256) void transpose64(
    const float* __restrict__ in, u16* __restrict__ out, int R, int Cstride)
{
  transpose_body(in, out, R, Cstride, blockIdx.x, blockIdx.y, threadIdx.x);
}

// merged kw/vw/qw transpose (identical 1024^2 geometry, z selects src/dst)
__global__ __launch_bounds__(256) void transpose3(
    const float* __restrict__ s0, const float* __restrict__ s1,
    const float* __restrict__ s2,
    u16* __restrict__ d0, u16* __restrict__ d1, u16* __restrict__ d2)
{
  const int z = blockIdx.z;
  const float* in = z == 0 ? s0 : (z == 1 ? s1 : s2);
  u16* out = z == 0 ? d0 : (z == 1 ? d1 : d2);
  transpose_body(in, out, 1024, 1024, blockIdx.x, blockIdx.y, threadIdx.x);
}

// ---------------------------------------------------------------------------
// Mask scan: per batch b, sidx[b][0..nv) = indices of valid (mask!=0) s2
// positions in ascending order; nv[b] = count. One block per b.
// ---------------------------------------------------------------------------
__global__ __launch_bounds__(256) void mask_scan(
    const int* __restrict__ mask, int* __restrict__ sidx, int* __restrict__ nv)
{
  const int b = blockIdx.x, t = threadIdx.x;
  const int wave = t >> 6, lane = t & 63;
  int m[4]; int cnt = 0;
#pragma unroll
  for (int k = 0; k < 4; ++k) { m[k] = (mask[b * 1024 + t * 4 + k] != 0); cnt += m[k]; }
  int sc = cnt;  // inclusive wave scan
  for (int sh = 1; sh < 64; sh <<= 1) {
    int u = __shfl_up(sc, sh);
    if (lane >= sh) sc += u;
  }
  __shared__ int wsum[4];
  if (lane == 63) wsum[wave] = sc;
  __syncthreads();
  int woff = 0;
  for (int w = 0; w < wave; ++w) woff += wsum[w];
  int pos = woff + sc - cnt;  // exclusive prefix
#pragma unroll
  for (int k = 0; k < 4; ++k)
    if (m[k]) sidx[b * 1024 + pos++] = t * 4 + k;
  if (t == 255) nv[b] = wsum[0] + wsum[1] + wsum[2] + wsum[3];
}

// ---------------------------------------------------------------------------
// Row gather: dst[b*1024+i] = src[b*1024 + sidx[min(i, nv-1)]] (bf16 rows of
// 1024). Pads tail rows with duplicates of the last valid row (finite data).
// Grid 1024, one row per wave.
// ---------------------------------------------------------------------------
__global__ __launch_bounds__(256) void gather_kv(
    const u16* __restrict__ src, const int* __restrict__ sidx,
    const int* __restrict__ nv, u16* __restrict__ dst)
{
  const int t = threadIdx.x, wave = t >> 6, lane = t & 63;
  const int row = blockIdx.x * 4 + wave;
  const int b = row >> 10, i = row & 1023;
  const int n = nv[b];
  const int s = sidx[b * 1024 + (i < n ? i : n - 1)];
  const uint4* sp = (const uint4*)&src[((size_t)(b << 10) + s) * 1024];
  uint4* dp = (uint4*)&dst[(size_t)row * 1024];
  dp[lane] = sp[lane];
  dp[lane + 64] = sp[lane + 64];
}

// ---------------------------------------------------------------------------
// Compacted V^T from compacted kvbuf v-half: out[(b*16+h)*64+d][i] =
// kvbuf[b*1024+min(i,n-1)][1024+h*64+d]. Clamp keeps all columns finite.
// ---------------------------------------------------------------------------
__global__ __launch_bounds__(256) void vtc_kernel(
    const u16* __restrict__ in, const int* __restrict__ nv,
    u16* __restrict__ out)
{
  __shared__ u16 tile[64][72];
  const int st = blockIdx.x, bh = blockIdx.y;
  const int b = bh >> 4, h = bh & 15;
  const int t = threadIdx.x;
  const int lr = t >> 3, lv = t & 7;
  const int n = nv[b];
  const u16* srcb = in + (size_t)b * 1024 * 2048 + 1024 + h * 64;
#pragma unroll
  for (int half = 0; half < 2; ++half) {
    int i = st * 64 + half * 32 + lr;               // compacted s2 index
    int s = i < n ? i : n - 1;                      // clamp -> finite data
    uint4 vd = *(const uint4*)&srcb[(size_t)s * 2048 + lv * 8];
    *(uint4*)&tile[half * 32 + lr][lv * 8] = vd;
  }
  __syncthreads();
  u16* dst = out + (size_t)bh * 64 * 1024 + st * 64;
#pragma unroll
  for (int half = 0; half < 2; ++half) {
    int orow = half * 32 + lr;  // d
    u16 tmp[8];
#pragma unroll
    for (int j = 0; j < 8; ++j) tmp[j] = tile[lv * 8 + j][orow];
    *(uint4*)&dst[(size_t)orow * 1024 + lv * 8] = *(uint4*)tmp;
  }
}

// ---------------------------------------------------------------------------
// LayerNorm over D=1024, fp32 in -> bf16 out.  ln_dual: one launch handles
// both LN1(x)->outx and LN1(kv)->outkv (grid 8192, launch-overhead merge).
// ---------------------------------------------------------------------------
__device__ __forceinline__ void ln_body(
    const float* x, const float* g, const float* b, u16* outbf,
    int row, int t)
{
  const int wave = t >> 6, lane = t & 63;
  float4 xv = *(const float4*)&x[(size_t)row * 1024 + t * 4];
  float v0 = xv.x, v1 = xv.y, v2 = xv.z, v3 = xv.w;
  float s = v0 + v1 + v2 + v3;
  float s2 = v0 * v0 + v1 * v1 + v2 * v2 + v3 * v3;
  for (int m = 1; m < 64; m <<= 1) { s += __shfl_xor(s, m); s2 += __shfl_xor(s2, m); }
  __shared__ float ps[4], pq[4];
  if (lane == 0) { ps[wave] = s; pq[wave] = s2; }
  __syncthreads();
  s = ps[0] + ps[1] + ps[2] + ps[3];
  s2 = pq[0] + pq[1] + pq[2] + pq[3];
  float mean = s * (1.f / 1024.f);
  float var = s2 * (1.f / 1024.f) - mean * mean;
  float rs = rsqrtf(var + 1e-5f);
  float4 gv = *(const float4*)&g[t * 4];
  float4 bv = *(const float4*)&b[t * 4];
  ushort4 ov;
  ov.x = f2bf((v0 - mean) * rs * gv.x + bv.x);
  ov.y = f2bf((v1 - mean) * rs * gv.y + bv.y);
  ov.z = f2bf((v2 - mean) * rs * gv.z + bv.z);
  ov.w = f2bf((v3 - mean) * rs * gv.w + bv.w);
  *(ushort4*)&outbf[(size_t)row * 1024 + t * 4] = ov;
}

__global__ __launch_bounds__(256) void ln_dual(
    const float* __restrict__ x, const float* __restrict__ kv,
    const float* __restrict__ g, const float* __restrict__ b,
    u16* __restrict__ outx, u16* __restrict__ outkv)
{
  const int row = blockIdx.x;  // block-uniform -> barrier in ln_body is safe
  if (row < 4096) ln_body(x, g, b, outx, row, threadIdx.x);
  else            ln_body(kv, g, b, outkv, row - 4096, threadIdx.x);
}

// h = LN(x + y), x fp32, y bf16.
__global__ __launch_bounds__(256) void ln_add_kernel(
    const float* __restrict__ x, const u16* __restrict__ ybf,
    const float* __restrict__ g, const float* __restrict__ b,
    u16* __restrict__ hbf)
{
  const int row = blockIdx.x, t = threadIdx.x;
  const int wave = t >> 6, lane = t & 63;
  float4 xv = *(const float4*)&x[(size_t)row * 1024 + t * 4];
  ushort4 yv = *(const ushort4*)&ybf[(size_t)row * 1024 + t * 4];
  float v0 = xv.x + bf2f(yv.x), v1 = xv.y + bf2f(yv.y);
  float v2 = xv.z + bf2f(yv.z), v3 = xv.w + bf2f(yv.w);
  float s = v0 + v1 + v2 + v3;
  float s2 = v0 * v0 + v1 * v1 + v2 * v2 + v3 * v3;
  for (int m = 1; m < 64; m <<= 1) { s += __shfl_xor(s, m); s2 += __shfl_xor(s2, m); }
  __shared__ float ps[4], pq[4];
  if (lane == 0) { ps[wave] = s; pq[wave] = s2; }
  __syncthreads();
  s = ps[0] + ps[1] + ps[2] + ps[3];
  s2 = pq[0] + pq[1] + pq[2] + pq[3];
  float mean = s * (1.f / 1024.f);
  float var = s2 * (1.f / 1024.f) - mean * mean;
  float rs = rsqrtf(var + 1e-5f);
  float4 gv = *(const float4*)&g[t * 4];
  float4 bv = *(const float4*)&b[t * 4];
  ushort4 ov;
  ov.x = f2bf((v0 - mean) * rs * gv.x + bv.x);
  ov.y = f2bf((v1 - mean) * rs * gv.y + bv.y);
  ov.z = f2bf((v2 - mean) * rs * gv.z + bv.z);
  ov.w = f2bf((v3 - mean) * rs * gv.w + bv.w);
  *(ushort4*)&hbf[(size_t)row * 1024 + t * 4] = ov;
}

// ---------------------------------------------------------------------------
// Flash-style cross-attention v8 (round-9 proven): QBLK=128, KVBLK=64,
// 4 waves, XCD-local grid, direct compacted K/V rows, jmax = ceil(nv/64).
// ---------------------------------------------------------------------------
__global__ __launch_bounds__(256) void attn_kernel(
    const u16* __restrict__ Q,   // [b*1024+s1][1024], head offset h*64
    const u16* __restrict__ K,   // compacted kvbuf [b*1024+i][2048], h*64
    const u16* __restrict__ Vt,  // compacted [(b*16+h)*64+d][1024]
    const int* __restrict__ nvp,
    u16* __restrict__ O)         // [b*1024+s1][1024]
{
  __shared__ u16 sK[64 * 64], sVt[64 * 64], sP[128 * 64];
  const int h = blockIdx.x, qt = blockIdx.y, b = blockIdx.z;
  const int t = threadIdx.x;
  const int wave = t >> 6, lane = t & 63;
  const int quad = lane >> 4, l16 = lane & 15;
  const u16* Qb = Q + (size_t)b * 1024 * 1024 + (size_t)qt * 128 * 1024 + h * 64;
  const u16* Kb = K + (size_t)b * 1024 * 2048 + h * 64;
  const u16* Vb = Vt + (size_t)(b * 16 + h) * 64 * 1024;
  const int n = nvp[b];
  const int jmax = (n + 63) >> 6;

  // stage Q [128 s1][64 dk] into sP (pre-swizzled source, linear LDS dest)
#pragma unroll
  for (int i = 0; i < 4; ++i) {
    int cb = i * 256 + wave * 64;
    int c = cb + lane;
    int row = c >> 3;
    int scc = (c & 7) ^ swzf(row);
    gl_lds16(Qb + (size_t)row * 1024 + scc * 8, &sP[cb * 8]);
  }
  __syncthreads();  // drain Q staging (cross-wave)
  bf16x8 aq[2][2];
#pragma unroll
  for (int g = 0; g < 2; ++g)
#pragma unroll
    for (int ks = 0; ks < 2; ++ks)
      aq[g][ks] = *(const bf16x8*)&sP[swz(wave * 32 + g * 16 + l16, ks * 32 + quad * 8)];

  float m2_[2][4], l_[2][4];
  f32x4 accO[2][4] = {};
#pragma unroll
  for (int g = 0; g < 2; ++g)
#pragma unroll
    for (int r = 0; r < 4; ++r) { m2_[g][r] = -1e30f; l_[g][r] = 0.f; }

  constexpr float QS = 0.125f * LOG2E;  // scale folded into base-2 domain

  for (int j = 0; j < jmax; ++j) {
    __syncthreads();  // prev iter's sK/sVt reads (and aq reads at j=0) done
    // sK/sVt: compacted rows, direct index (rows < ceil64(n) all computed).
#pragma unroll
    for (int i = 0; i < 2; ++i) {
      int cb = i * 256 + wave * 64;
      int c = cb + lane;
      int row = c >> 3;
      int scc = (c & 7) ^ swzf(row);
      gl_lds16(Kb + (size_t)(j * 64 + row) * 2048 + scc * 8, &sK[cb * 8]);
      gl_lds16(Vb + (size_t)row * 1024 + j * 64 + scc * 8, &sVt[cb * 8]);
    }
    __syncthreads();  // drains vmcnt: sK/sVt staged

    float mf[4];
#pragma unroll
    for (int nt = 0; nt < 4; ++nt)
      mf[nt] = (j * 64 + nt * 16 + l16 < n) ? 0.f : -1e9f;

    // per 16-row group: S = Q K^T, online softmax, P -> sP (wave-private rows)
#pragma unroll
    for (int g = 0; g < 2; ++g) {
      f32x4 accS[4] = {};
#pragma unroll
      for (int ks = 0; ks < 2; ++ks) {
#pragma unroll
        for (int nt = 0; nt < 4; ++nt) {
          bf16x8 bk = *(const bf16x8*)&sK[swz(nt * 16 + l16, ks * 32 + quad * 8)];
          accS[nt] = __builtin_amdgcn_mfma_f32_16x16x32_bf16(aq[g][ks], bk, accS[nt], 0, 0, 0);
        }
      }
      float vv[4][4], cm_[4];
      bool need = false;
#pragma unroll
      for (int r = 0; r < 4; ++r) {
#pragma unroll
        for (int nt = 0; nt < 4; ++nt) vv[r][nt] = fmaf(accS[nt][r], QS, mf[nt]);
        float cm = fmaxf(fmaxf(vv[r][0], vv[r][1]), fmaxf(vv[r][2], vv[r][3]));
        for (int sh = 1; sh < 16; sh <<= 1) cm = fmaxf(cm, __shfl_xor(cm, sh));
        cm_[r] = cm;
        need = need || (cm > m2_[g][r] + 8.f);
      }
      if (__any(need)) {  // T13 defer-max: rescale only when a max grew by >8
#pragma unroll
        for (int r = 0; r < 4; ++r) {
          float nm = fmaxf(m2_[g][r], cm_[r]);
          float al = exp2f(m2_[g][r] - nm);
          m2_[g][r] = nm;
          l_[g][r] *= al;
#pragma unroll
          for (int n2 = 0; n2 < 4; ++n2) accO[g][n2][r] *= al;
        }
      }
#pragma unroll
      for (int r = 0; r < 4; ++r) {
        int prow = wave * 32 + g * 16 + quad * 4 + r;
        float rs = 0.f;
#pragma unroll
        for (int nt = 0; nt < 4; ++nt) {
          float p = exp2f(vv[r][nt] - m2_[g][r]);
          rs += p;
          sP[swz(prow, nt * 16 + l16)] = f2bf_fast(p);
        }
        l_[g][r] += rs;  // per-lane partial sum; reduced after the loop
      }
    }
    // O += P @ V.  No barrier: sP rows are wave-private; V frags shared
    // across both row groups (read once per ks).
#pragma unroll
    for (int ks = 0; ks < 2; ++ks) {
      bf16x8 bv[4];
#pragma unroll
      for (int n2 = 0; n2 < 4; ++n2)
        bv[n2] = *(const bf16x8*)&sVt[swz(n2 * 16 + l16, ks * 32 + quad * 8)];
#pragma unroll
      for (int g = 0; g < 2; ++g) {
        bf16x8 ap = *(const bf16x8*)&sP[swz(wave * 32 + g * 16 + l16, ks * 32 + quad * 8)];
#pragma unroll
        for (int n2 = 0; n2 < 4; ++n2)
          accO[g][n2] = __builtin_amdgcn_mfma_f32_16x16x32_bf16(ap, bv[n2], accO[g][n2], 0, 0, 0);
      }
    }
  }

  // final l reduce across the 16 l16 lanes of each row (deferred from loop)
  u16* Ob = O + (size_t)b * 1024 * 1024 + (size_t)qt * 128 * 1024 + h * 64;
#pragma unroll
  for (int g = 0; g < 2; ++g) {
#pragma unroll
    for (int r = 0; r < 4; ++r) {
      float lr = l_[g][r];
      for (int sh = 1; sh < 16; sh <<= 1) lr += __shfl_xor(lr, sh);
      float inv = 1.f / lr;
      int row = wave * 32 + g * 16 + quad * 4 + r;
#pragma unroll
      for (int n2 = 0; n2 < 4; ++n2)
        Ob[(size_t)row * 1024 + n2 * 16 + l16] = f2bf_fast(accO[g][n2][r] * inv);
    }
  }
}

// ---------------------------------------------------------------------------
extern "C" void kernel_launch(void* const* d_in, const int* in_sizes, int n_in,
                              void* d_out, int out_size, void* d_ws, size_t ws_size,
                              hipStream_t stream)
{
  const float* x   = (const float*)d_in[0];
  const float* kv  = (const float*)d_in[1];
  const int* attn_bias = (const int*)d_in[2];
  const float* ln1_g = (const float*)d_in[3];
  const float* ln1_b = (const float*)d_in[4];
  const float* qw0 = (const float*)d_in[5];
  const float* kw0 = (const float*)d_in[6];
  const float* vw0 = (const float*)d_in[7];
  const float* ow0 = (const float*)d_in[8];
  const float* ob0 = (const float*)d_in[9];
  const float* qw1 = (const float*)d_in[10];
  const float* kw1 = (const float*)d_in[11];
  const float* vw1 = (const float*)d_in[12];
  const float* ow1 = (const float*)d_in[13];
  const float* ob1 = (const float*)d_in[14];
  const float* ln2_g = (const float*)d_in[15];
  const float* ln2_b = (const float*)d_in[16];
  const float* w1 = (const float*)d_in[17];
  const float* b1 = (const float*)d_in[18];
  const float* w2 = (const float*)d_in[19];
  const float* b2 = (const float*)d_in[20];

  // ---- workspace: 48 MB peak (proven safe), d_out doubles as scratch ----
  char* ws = (char*)d_ws;
  const size_t MB = 1u << 20;
  u16* Wkv   = (u16*)(ws + 0 * MB);    // stacked kv weight-T [2048,1024] 4MB
  u16* Wsm   = (u16*)(ws + 4 * MB);    // q/o weight-T [1024,1024] 2MB (serial)
  int* sidx  = (int*)(ws + 6 * MB);    // 16KB+16B (free gap; FFN reuses later)
  int* nvp   = sidx + 4096;
  u16* wtA   = (u16*)(ws + 0 * MB);    // FFN band w1-T [2048,1024] 4MB
  u16* wtB   = (u16*)(ws + 4 * MB);    // FFN band w2-T [1024,2048] 4MB
  u16* ybf   = (u16*)(ws + 8 * MB);    // residual y bf16 8MB
  u16* kvc   = (u16*)(ws + 16 * MB);   // compacted LN1(kv) 8MB; hbf aliases
  u16* qbuf  = (u16*)(ws + 24 * MB);   // q bf16 8MB (also LN1(kv) temp)
  u16* kvbuf = (u16*)(ws + 32 * MB);   // [4096,2048] k|v compacted 16MB
  u16* hbf   = kvc;                    // ln_add output (kvc dead by then)
  u16* fbuf  = kvbuf;                  // [4096,2048] bf16 16MB
  u16* attnb = (u16*)d_out;                      // lower 8MB of d_out
  u16* vT    = (u16*)((char*)d_out + 8 * MB);    // upper 8MB of d_out
  float* out32 = (float*)d_out;

  const dim3 B256(256);
  const dim3 gT3(16, 16, 3);     // merged kw/vw/qw transpose
  const dim3 gT(16, 16);         // 1024x1024 weight transpose (ow)
  const dim3 gGemmN1k(8, 64);    // <64,128>  N=1024: 512 blocks
  const dim3 gGemm2k(16, 64);    // <64,128>  N=2048: 1024 blocks
  const dim3 gVt(16, 64);
  const dim3 gAttn(16, 8, 4);    // (h, qt, b): qt stride 16 = 0 mod 8 XCDs

  // --- mask compaction (mask is layer-invariant: run once) ---
  mask_scan<<<4, B256, 0, stream>>>(attn_bias, sidx, nvp);

  // --- LN1 (both tensors, one launch); kv normed into qbuf (temp),
  //     then row-compacted into kvc ---
  ln_dual<<<8192, B256, 0, stream>>>(x, kv, ln1_g, ln1_b, ybf, qbuf);
  gather_kv<<<1024, B256, 0, stream>>>(qbuf, sidx, nvp, kvc);

  for (int layer = 0; layer < 2; ++layer) {
    const float* qw = layer ? qw1 : qw0;
    const float* kw = layer ? kw1 : kw0;
    const float* vw = layer ? vw1 : vw0;
    const float* ow = layer ? ow1 : ow0;
    const float* ob = layer ? ob1 : ob0;

    // merged transpose: Wkv = [kw^T ; vw^T], Wsm = qw^T (one launch)
    transpose3<<<gT3, B256, 0, stream>>>(kw, vw, qw,
                                         Wkv, Wkv + 1024 * 1024, Wsm);
    // fused k|v projection on COMPACTED rows
    gemm_bt<64, 128, 0><<<gGemm2k, B256, 0, stream>>>(
        kvc, Wkv, kvbuf, nullptr, nullptr, nullptr, nullptr,
        4096, 2048, 1024, nvp);
    // q projection
    gemm_bt<64, 128, 0><<<gGemmN1k, B256, 0, stream>>>(
        ybf, Wsm, qbuf, nullptr, nullptr, nullptr, nullptr,
        4096, 1024, 1024, nullptr);
    // compacted V^T materialization from compacted kvbuf v-half
    vtc_kernel<<<gVt, B256, 0, stream>>>(kvbuf, nvp, vT);

    attn_kernel<<<gAttn, B256, 0, stream>>>(qbuf, kvbuf, vT, nvp, attnb);

    // y = attn_out @ ow + ob + y
    transpose64<<<gT, B256, 0, stream>>>(ow, Wsm, 1024, 1024);
    gemm_bt<64, 128, 1><<<gGemmN1k, B256, 0, stream>>>(
        attnb, Wsm, ybf, nullptr, ob, ybf, nullptr,
        4096, 1024, 1024, nullptr);
  }

  // --- h = LN2(x + y) ---
  ln_add_kernel<<<4096, B256, 0, stream>>>(x, ybf, ln2_g, ln2_b, hbf);

  // --- FFN in two K-bands of 2048; fp32 accumulate into d_out ---
  for (int band = 0; band < 2; ++band) {
    transpose64<<<dim3(32, 16), B256, 0, stream>>>(w1 + band * 2048, wtA, 1024, 4096);
    transpose64<<<dim3(16, 32), B256, 0, stream>>>(w2 + (size_t)band * 2048 * 1024,
                                                   wtB, 2048, 1024);
    gemm_bt<64, 128, 2><<<gGemm2k, B256, 0, stream>>>(
        hbf, wtA, fbuf, nullptr, b1 + band * 2048, nullptr, nullptr,
        4096, 2048, 1024, nullptr);
    if (band == 0) {
      gemm_bt<64, 128, 3><<<gGemmN1k, B256, 0, stream>>>(
          fbuf, wtB, nullptr, out32, b2, ybf, x, 4096, 1024, 2048, nullptr);
    } else {
      gemm_bt<64, 128, 4><<<gGemmN1k, B256, 0, stream>>>(
          fbuf, wtB, nullptr, out32, nullptr, nullptr, nullptr,
          4096, 1024, 2048, nullptr);
    }
  }
}